// Round 1
// baseline (363.111 us; speedup 1.0000x reference)
//
#include <hip/hip_runtime.h>
#include <cstdint>
#include <math.h>

#define IMH 2048
#define IMW 2048
#define NB 4
#define NPIX (NB*IMH*IMW)        // 16777216
#define MEDRANK ((NPIX-1)/2)     // 8388607
#define ALPHA 0.05f

#define TW 64
#define TH 32

__device__ __forceinline__ uint32_t fkey(float f){
  uint32_t u = __float_as_uint(f);
  return (u & 0x80000000u) ? ~u : (u | 0x80000000u);
}

__device__ __forceinline__ float ldz(const float* __restrict__ p, int r, int c){
  return (r >= 0 && r < IMH && c >= 0 && c < IMW) ? p[(size_t)r*IMW + c] : 0.f;
}

// ---------------------------------------------------------------------------
// Fused: Sobel -> products -> separable 9x9 Gaussian -> Harris R
// Tile: 64 wide x 32 tall. LDS ~62KB -> 2 blocks/CU.
// ---------------------------------------------------------------------------
__global__ __launch_bounds__(256) void front_kernel(
    const float* __restrict__ x, const float* __restrict__ sobel_w,
    const float* __restrict__ gauss_w, float* __restrict__ R)
{
  __shared__ float xs[TH+10][TW+16];    // 42 x 80, rows R0-5.., cols C0-8..
  __shared__ float ps[3][TH+8][TW+16];  // 40 x 80, rows R0-4.., cols C0-8..
  __shared__ float hs[TH+8][TW];        // 40 x 64, rows R0-4.., cols C0..

  const int tid = threadIdx.x;
  const int C0 = blockIdx.x * TW;
  const int R0 = blockIdx.y * TH;
  const int n  = blockIdx.z;
  const float* xb = x + (size_t)n * (size_t)(IMH*IMW);

  float w0[9], w1[9];
#pragma unroll
  for (int i = 0; i < 9; i++){ w0[i] = sobel_w[i]; w1[i] = sobel_w[9+i]; }
  float ga[9];
  {
    float a4 = sqrtf(gauss_w[4*9+4]);
#pragma unroll
    for (int i = 0; i < 9; i++) ga[i] = gauss_w[4*9+i] / a4;
  }

  // ---- load x tile (zero padded) ----
  for (int u = tid; u < (TH+10)*20; u += 256){
    int r  = u / 20, c4 = u % 20;
    int gr = R0 - 5 + r;
    int gc = C0 - 8 + c4*4;
    float4 v;
    if (gr >= 0 && gr < IMH && gc >= 0 && gc + 3 < IMW){
      v = *reinterpret_cast<const float4*>(&xb[(size_t)gr*IMW + gc]);
    } else {
      v.x = ldz(xb, gr, gc+0);
      v.y = ldz(xb, gr, gc+1);
      v.z = ldz(xb, gr, gc+2);
      v.w = ldz(xb, gr, gc+3);
    }
    *reinterpret_cast<float4*>(&xs[r][c4*4]) = v;
  }
  __syncthreads();

  // ---- Sobel + products into 3 LDS planes (region cols C0-4..C0+67) ----
  for (int u = tid; u < (TH+8)*18; u += 256){
    int r  = u / 18;
    int c4 = u % 18 + 1;          // f4 index 1..18
    int cb = c4*4;
    int gr = R0 - 4 + r;
    float rw[3][12];
#pragma unroll
    for (int i = 0; i < 3; i++){
      float4 a = *reinterpret_cast<const float4*>(&xs[r+i][cb-4]);
      float4 b = *reinterpret_cast<const float4*>(&xs[r+i][cb]);
      float4 c = *reinterpret_cast<const float4*>(&xs[r+i][cb+4]);
      rw[i][0]=a.x; rw[i][1]=a.y; rw[i][2]=a.z; rw[i][3]=a.w;
      rw[i][4]=b.x; rw[i][5]=b.y; rw[i][6]=b.z; rw[i][7]=b.w;
      rw[i][8]=c.x; rw[i][9]=c.y; rw[i][10]=c.z; rw[i][11]=c.w;
    }
    float o0[4], o1[4], o2[4];
#pragma unroll
    for (int j = 0; j < 4; j++){
      int gc = C0 - 8 + cb + j;
      float ix = 0.f, iy = 0.f;
#pragma unroll
      for (int i = 0; i < 3; i++){
#pragma unroll
        for (int d = 0; d < 3; d++){
          float xv = rw[i][3 + j + d];
          ix = fmaf(w0[i*3+d], xv, ix);
          iy = fmaf(w1[i*3+d], xv, iy);
        }
      }
      bool valid = (gr >= 0 && gr < IMH && gc >= 0 && gc < IMW);
      o0[j] = valid ? ix*ix : 0.f;
      o1[j] = valid ? iy*iy : 0.f;
      o2[j] = valid ? ix*iy : 0.f;
    }
    *reinterpret_cast<float4*>(&ps[0][r][cb]) = make_float4(o0[0],o0[1],o0[2],o0[3]);
    *reinterpret_cast<float4*>(&ps[1][r][cb]) = make_float4(o1[0],o1[1],o1[2],o1[3]);
    *reinterpret_cast<float4*>(&ps[2][r][cb]) = make_float4(o2[0],o2[1],o2[2],o2[3]);
  }
  __syncthreads();

  const int c4o = tid & 15;
  const int r0o = (tid >> 4) * 2;
  float4 sA[3], sB[3];

#pragma unroll
  for (int p = 0; p < 3; p++){
    // horizontal Gaussian for plane p
    for (int u = tid; u < (TH+8)*16; u += 256){
      int r  = u / 16, c4 = u % 16;
      float4 t0 = *reinterpret_cast<const float4*>(&ps[p][r][c4*4+4]);
      float4 t1 = *reinterpret_cast<const float4*>(&ps[p][r][c4*4+8]);
      float4 t2 = *reinterpret_cast<const float4*>(&ps[p][r][c4*4+12]);
      float w[12];
      w[0]=t0.x; w[1]=t0.y; w[2]=t0.z; w[3]=t0.w;
      w[4]=t1.x; w[5]=t1.y; w[6]=t1.z; w[7]=t1.w;
      w[8]=t2.x; w[9]=t2.y; w[10]=t2.z; w[11]=t2.w;
      float o[4];
#pragma unroll
      for (int j = 0; j < 4; j++){
        float s = 0.f;
#pragma unroll
        for (int k = 0; k < 9; k++) s = fmaf(ga[k], w[j+k], s);
        o[j] = s;
      }
      *reinterpret_cast<float4*>(&hs[r][c4*4]) = make_float4(o[0],o[1],o[2],o[3]);
    }
    __syncthreads();
    // vertical Gaussian, 2 output rows per thread
    {
      float4 a0 = make_float4(0,0,0,0), a1 = make_float4(0,0,0,0);
#pragma unroll
      for (int k = 0; k < 10; k++){
        float4 hv = *reinterpret_cast<const float4*>(&hs[r0o+k][c4o*4]);
        if (k < 9){
          a0.x = fmaf(ga[k], hv.x, a0.x); a0.y = fmaf(ga[k], hv.y, a0.y);
          a0.z = fmaf(ga[k], hv.z, a0.z); a0.w = fmaf(ga[k], hv.w, a0.w);
        }
        if (k >= 1){
          a1.x = fmaf(ga[k-1], hv.x, a1.x); a1.y = fmaf(ga[k-1], hv.y, a1.y);
          a1.z = fmaf(ga[k-1], hv.z, a1.z); a1.w = fmaf(ga[k-1], hv.w, a1.w);
        }
      }
      sA[p] = a0; sB[p] = a1;
    }
    __syncthreads();
  }

  // ---- Harris response, write 2 rows x 4 cols ----
  float* Rb = R + (size_t)n * (size_t)(IMH*IMW);
  {
    float4 o0, o1;
    {
      float s0, s1, s2, det, tr;
      s0=sA[0].x; s1=sA[1].x; s2=sA[2].x; det=s0*s1-s2*s2; tr=s0+s1; o0.x=det-ALPHA*tr*tr;
      s0=sA[0].y; s1=sA[1].y; s2=sA[2].y; det=s0*s1-s2*s2; tr=s0+s1; o0.y=det-ALPHA*tr*tr;
      s0=sA[0].z; s1=sA[1].z; s2=sA[2].z; det=s0*s1-s2*s2; tr=s0+s1; o0.z=det-ALPHA*tr*tr;
      s0=sA[0].w; s1=sA[1].w; s2=sA[2].w; det=s0*s1-s2*s2; tr=s0+s1; o0.w=det-ALPHA*tr*tr;
      s0=sB[0].x; s1=sB[1].x; s2=sB[2].x; det=s0*s1-s2*s2; tr=s0+s1; o1.x=det-ALPHA*tr*tr;
      s0=sB[0].y; s1=sB[1].y; s2=sB[2].y; det=s0*s1-s2*s2; tr=s0+s1; o1.y=det-ALPHA*tr*tr;
      s0=sB[0].z; s1=sB[1].z; s2=sB[2].z; det=s0*s1-s2*s2; tr=s0+s1; o1.z=det-ALPHA*tr*tr;
      s0=sB[0].w; s1=sB[1].w; s2=sB[2].w; det=s0*s1-s2*s2; tr=s0+s1; o1.w=det-ALPHA*tr*tr;
    }
    int orow = R0 + r0o;
    int ocol = C0 + c4o*4;
    *reinterpret_cast<float4*>(&Rb[(size_t)orow*IMW + ocol])     = o0;
    *reinterpret_cast<float4*>(&Rb[(size_t)(orow+1)*IMW + ocol]) = o1;
  }
}

// ---------------------------------------------------------------------------
// Median: 3-pass radix select (8 / 12 / 12 bits) on monotonic key transform
// ---------------------------------------------------------------------------
__global__ __launch_bounds__(256) void hist8_kernel(
    const float4* __restrict__ R4, uint32_t* __restrict__ h)
{
  __shared__ uint32_t lh[256];
  lh[threadIdx.x] = 0;
  __syncthreads();
  const int stride = gridDim.x * 256;
  for (int i = blockIdx.x*256 + threadIdx.x; i < NPIX/4; i += stride){
    float4 v = R4[i];
    atomicAdd(&lh[fkey(v.x) >> 24], 1u);
    atomicAdd(&lh[fkey(v.y) >> 24], 1u);
    atomicAdd(&lh[fkey(v.z) >> 24], 1u);
    atomicAdd(&lh[fkey(v.w) >> 24], 1u);
  }
  __syncthreads();
  if (lh[threadIdx.x]) atomicAdd(&h[threadIdx.x], lh[threadIdx.x]);
}

__global__ __launch_bounds__(256) void hist12_kernel(
    const float4* __restrict__ R4, uint32_t* __restrict__ h,
    const uint32_t* __restrict__ state, int phase)
{
  __shared__ uint32_t lh[4096];
  for (int i = threadIdx.x; i < 4096; i += 256) lh[i] = 0;
  __syncthreads();
  const uint32_t target = (phase == 0) ? state[0] : ((state[0] << 12) | state[2]);
  const int shift = (phase == 0) ? 24 : 12;
  const int stride = gridDim.x * 256;
  for (int i = blockIdx.x*256 + threadIdx.x; i < NPIX/4; i += stride){
    float4 v = R4[i];
    uint32_t k;
    k = fkey(v.x); if ((k >> shift) == target) atomicAdd(&lh[(k >> (shift-12)) & 0xfffu], 1u);
    k = fkey(v.y); if ((k >> shift) == target) atomicAdd(&lh[(k >> (shift-12)) & 0xfffu], 1u);
    k = fkey(v.z); if ((k >> shift) == target) atomicAdd(&lh[(k >> (shift-12)) & 0xfffu], 1u);
    k = fkey(v.w); if ((k >> shift) == target) atomicAdd(&lh[(k >> (shift-12)) & 0xfffu], 1u);
  }
  __syncthreads();
  for (int i = threadIdx.x; i < 4096; i += 256)
    if (lh[i]) atomicAdd(&h[i], lh[i]);
}

__global__ __launch_bounds__(256) void select_kernel(
    const uint32_t* __restrict__ h, uint32_t* __restrict__ state,
    int nbins, int phase)
{
  __shared__ uint32_t sc[256];
  const int t = threadIdx.x;
  const int chunk = nbins >> 8;   // 1 or 16
  uint32_t lsum = 0;
  for (int i = 0; i < chunk; i++) lsum += h[t*chunk + i];
  sc[t] = lsum;
  __syncthreads();
  for (int off = 1; off < 256; off <<= 1){
    uint32_t v = (t >= off) ? sc[t-off] : 0u;
    __syncthreads();
    sc[t] += v;
    __syncthreads();
  }
  const uint32_t excl = sc[t] - lsum;
  const uint32_t rank = (phase == 0) ? (uint32_t)MEDRANK : state[(phase == 1) ? 1 : 3];
  if (rank >= excl && rank < excl + lsum){
    uint32_t cum = excl;
    for (int i = 0; i < chunk; i++){
      uint32_t c = h[t*chunk + i];
      if (rank < cum + c){
        uint32_t bin = (uint32_t)(t*chunk + i);
        if (phase == 0){ state[0] = bin; state[1] = rank - cum; }
        else if (phase == 1){ state[2] = bin; state[3] = rank - cum; }
        else {
          uint32_t key = (state[0] << 24) | (state[2] << 12) | bin;
          uint32_t u = (key & 0x80000000u) ? (key & 0x7fffffffu) : ~key;
          state[4] = u;
        }
        break;
      }
      cum += c;
    }
  }
}

// ---------------------------------------------------------------------------
// Threshold + 7x7 maxpool NMS. Tile 64x64, halo 3.
// ---------------------------------------------------------------------------
#define PT 64
__global__ __launch_bounds__(256) void nms_kernel(
    const float* __restrict__ R, const uint32_t* __restrict__ state,
    float* __restrict__ out)
{
  __shared__ float xt[PT+6][PT+8];   // 70 x 72, rows R0-3.., cols C0-4..
  __shared__ float hm[PT+6][PT];     // 70 x 64, rows R0-3.., cols C0..

  const int tid = threadIdx.x;
  const int C0 = blockIdx.x * PT;
  const int R0 = blockIdx.y * PT;
  const int n  = blockIdx.z;
  const float med = __uint_as_float(state[4]);
  const float* Rb = R + (size_t)n * (size_t)(IMH*IMW);

  for (int u = tid; u < 70*18; u += 256){
    int r  = u / 18, c4 = u % 18;
    int gr = R0 - 3 + r;
    int gc = C0 - 4 + c4*4;
    float4 v;
    if (gr >= 0 && gr < IMH && gc >= 0 && gc + 3 < IMW){
      v = *reinterpret_cast<const float4*>(&Rb[(size_t)gr*IMW + gc]);
      v.x = v.x > med ? v.x : 0.f;
      v.y = v.y > med ? v.y : 0.f;
      v.z = v.z > med ? v.z : 0.f;
      v.w = v.w > med ? v.w : 0.f;
    } else {
      float t0, t1, t2, t3;
      t0 = (gr>=0&&gr<IMH&&gc+0>=0&&gc+0<IMW) ? Rb[(size_t)gr*IMW+gc+0] : -INFINITY;
      t1 = (gr>=0&&gr<IMH&&gc+1>=0&&gc+1<IMW) ? Rb[(size_t)gr*IMW+gc+1] : -INFINITY;
      t2 = (gr>=0&&gr<IMH&&gc+2>=0&&gc+2<IMW) ? Rb[(size_t)gr*IMW+gc+2] : -INFINITY;
      t3 = (gr>=0&&gr<IMH&&gc+3>=0&&gc+3<IMW) ? Rb[(size_t)gr*IMW+gc+3] : -INFINITY;
      v.x = (t0 == -INFINITY) ? t0 : (t0 > med ? t0 : 0.f);
      v.y = (t1 == -INFINITY) ? t1 : (t1 > med ? t1 : 0.f);
      v.z = (t2 == -INFINITY) ? t2 : (t2 > med ? t2 : 0.f);
      v.w = (t3 == -INFINITY) ? t3 : (t3 > med ? t3 : 0.f);
    }
    *reinterpret_cast<float4*>(&xt[r][c4*4]) = v;
  }
  __syncthreads();

  for (int u = tid; u < 70*16; u += 256){
    int r = u / 16, c4 = u % 16;
    float4 t0 = *reinterpret_cast<const float4*>(&xt[r][c4*4]);
    float4 t1 = *reinterpret_cast<const float4*>(&xt[r][c4*4+4]);
    float4 t2 = *reinterpret_cast<const float4*>(&xt[r][c4*4+8]);
    float w[12];
    w[0]=t0.x; w[1]=t0.y; w[2]=t0.z; w[3]=t0.w;
    w[4]=t1.x; w[5]=t1.y; w[6]=t1.z; w[7]=t1.w;
    w[8]=t2.x; w[9]=t2.y; w[10]=t2.z; w[11]=t2.w;
    float o[4];
#pragma unroll
    for (int j = 0; j < 4; j++){
      float m = w[j+1];
#pragma unroll
      for (int k = 2; k <= 7; k++) m = fmaxf(m, w[j+k]);
      o[j] = m;
    }
    *reinterpret_cast<float4*>(&hm[r][c4*4]) = make_float4(o[0],o[1],o[2],o[3]);
  }
  __syncthreads();

  const int c4o = tid & 15;
  const int r0o = (tid >> 4) * 4;
  float4 hv[10];
#pragma unroll
  for (int k = 0; k < 10; k++)
    hv[k] = *reinterpret_cast<const float4*>(&hm[r0o+k][c4o*4]);

  float* ob = out + (size_t)n * (size_t)(IMH*IMW);
#pragma unroll
  for (int i = 0; i < 4; i++){
    float4 y = hv[i];
#pragma unroll
    for (int k = 1; k < 7; k++){
      float4 t = hv[i+k];
      y.x = fmaxf(y.x, t.x); y.y = fmaxf(y.y, t.y);
      y.z = fmaxf(y.z, t.z); y.w = fmaxf(y.w, t.w);
    }
    float4 c = *reinterpret_cast<const float4*>(&xt[r0o+i+3][c4o*4+4]);
    float4 o;
    o.x = (c.x == y.x) ? c.x : 0.f;
    o.y = (c.y == y.y) ? c.y : 0.f;
    o.z = (c.z == y.z) ? c.z : 0.f;
    o.w = (c.w == y.w) ? c.w : 0.f;
    *reinterpret_cast<float4*>(&ob[(size_t)(R0+r0o+i)*IMW + C0 + c4o*4]) = o;
  }
}

// ---------------------------------------------------------------------------
extern "C" void kernel_launch(void* const* d_in, const int* in_sizes, int n_in,
                              void* d_out, int out_size, void* d_ws, size_t ws_size,
                              hipStream_t stream)
{
  (void)in_sizes; (void)n_in; (void)out_size; (void)ws_size;
  const float* x  = (const float*)d_in[0];
  const float* sw = (const float*)d_in[1];
  const float* gw = (const float*)d_in[2];
  float* out = (float*)d_out;

  float* R = (float*)d_ws;
  uint32_t* hist = (uint32_t*)((char*)d_ws + (size_t)NPIX * sizeof(float));
  uint32_t* h8    = hist;
  uint32_t* h12a  = hist + 256;
  uint32_t* h12b  = hist + 256 + 4096;
  uint32_t* state = hist + 256 + 4096 + 4096;

  hipMemsetAsync(hist, 0, (256 + 4096 + 4096) * sizeof(uint32_t), stream);

  front_kernel<<<dim3(IMW/TW, IMH/TH, NB), 256, 0, stream>>>(x, sw, gw, R);

  hist8_kernel <<<1024, 256, 0, stream>>>((const float4*)R, h8);
  select_kernel<<<1,    256, 0, stream>>>(h8, state, 256, 0);
  hist12_kernel<<<1024, 256, 0, stream>>>((const float4*)R, h12a, state, 0);
  select_kernel<<<1,    256, 0, stream>>>(h12a, state, 4096, 1);
  hist12_kernel<<<1024, 256, 0, stream>>>((const float4*)R, h12b, state, 1);
  select_kernel<<<1,    256, 0, stream>>>(h12b, state, 4096, 2);

  nms_kernel<<<dim3(IMW/PT, IMH/PT, NB), 256, 0, stream>>>(R, state, out);
}

// Round 2
// 303.619 us; speedup vs baseline: 1.1959x; 1.1959x over previous
//
#include <hip/hip_runtime.h>
#include <cstdint>
#include <math.h>

#define IMH 2048
#define IMW 2048
#define NB 4
#define NPIX (NB*IMH*IMW)        // 16777216
#define MEDRANK ((NPIX-1)/2)     // 8388607
#define ALPHA 0.05f

#define TW 64
#define TH 32

__device__ __forceinline__ uint32_t fkey(float f){
  uint32_t u = __float_as_uint(f);
  return (u & 0x80000000u) ? ~u : (u | 0x80000000u);
}

__device__ __forceinline__ float ldz(const float* __restrict__ p, int r, int c){
  return (r >= 0 && r < IMH && c >= 0 && c < IMW) ? p[(size_t)r*IMW + c] : 0.f;
}

// ---------------------------------------------------------------------------
// Fused: Sobel -> products -> separable 9x9 Gaussian -> Harris R
// Tile: 64 wide x 32 tall, 256 threads.
// LDS: xs 42x84 (14.1KB) + hs 3x40x68 (32.6KB) = 46.8KB -> 3 blocks/CU.
// Two barriers total. Sobel recomputed inside the horizontal pass (3x column
// redundancy) to skip materializing the 3 product planes in LDS.
// ---------------------------------------------------------------------------
__global__ __launch_bounds__(256) void front_kernel(
    const float* __restrict__ x, const float* __restrict__ sobel_w,
    const float* __restrict__ gauss_w, float* __restrict__ R)
{
  __shared__ float xs[TH+10][84];       // rows R0-5..R0+36, cols C0-8..C0+71
  __shared__ float hs[3][TH+8][68];     // rows R0-4..R0+35, cols C0..C0+63

  const int tid = threadIdx.x;
  const int C0 = blockIdx.x * TW;
  const int R0 = blockIdx.y * TH;
  const int n  = blockIdx.z;
  const float* xb = x + (size_t)n * (size_t)(IMH*IMW);

  float w0[9], w1[9];
#pragma unroll
  for (int i = 0; i < 9; i++){ w0[i] = sobel_w[i]; w1[i] = sobel_w[9+i]; }
  float ga[9];
  {
    float a4 = sqrtf(gauss_w[4*9+4]);
#pragma unroll
    for (int i = 0; i < 9; i++) ga[i] = gauss_w[4*9+i] / a4;
  }

  // ---- load x tile (zero padded), 42 rows x 80 cols ----
  for (int u = tid; u < (TH+10)*20; u += 256){
    int r  = u / 20, c4 = u % 20;
    int gr = R0 - 5 + r;
    int gc = C0 - 8 + c4*4;
    float4 v;
    if (gr >= 0 && gr < IMH && gc >= 0 && gc + 3 < IMW){
      v = *reinterpret_cast<const float4*>(&xb[(size_t)gr*IMW + gc]);
    } else {
      v.x = ldz(xb, gr, gc+0);
      v.y = ldz(xb, gr, gc+1);
      v.z = ldz(xb, gr, gc+2);
      v.w = ldz(xb, gr, gc+3);
    }
    *reinterpret_cast<float4*>(&xs[r][c4*4]) = v;
  }
  __syncthreads();

  // ---- fused Sobel + products + horizontal Gaussian, all 3 planes ----
  // hs row hr <-> product row gr = R0-4+hr ; out col group oc..oc+3
  for (int u = tid; u < (TH+8)*16; u += 256){
    int hr = u >> 4;
    int oc = (u & 15) * 4;
    int gr = R0 - 4 + hr;
    bool rowv = ((unsigned)gr < (unsigned)IMH);

    float ix[12], iy[12];
#pragma unroll
    for (int j = 0; j < 12; j++){ ix[j] = 0.f; iy[j] = 0.f; }
#pragma unroll
    for (int i = 0; i < 3; i++){
      float xr[20];
#pragma unroll
      for (int m = 0; m < 5; m++){
        float4 t = *reinterpret_cast<const float4*>(&xs[hr+i][oc + m*4]);
        xr[m*4+0]=t.x; xr[m*4+1]=t.y; xr[m*4+2]=t.z; xr[m*4+3]=t.w;
      }
#pragma unroll
      for (int j = 0; j < 12; j++){
#pragma unroll
        for (int d = 0; d < 3; d++){
          float xv = xr[3 + j + d];
          ix[j] = fmaf(w0[i*3+d], xv, ix[j]);
          iy[j] = fmaf(w1[i*3+d], xv, iy[j]);
        }
      }
    }
    float pr[3][12];
#pragma unroll
    for (int j = 0; j < 12; j++){
      int gc = C0 + oc - 4 + j;
      bool v = rowv && ((unsigned)gc < (unsigned)IMW);
      float a = v ? ix[j] : 0.f;
      float b = v ? iy[j] : 0.f;
      pr[0][j] = a*a; pr[1][j] = b*b; pr[2][j] = a*b;
    }
#pragma unroll
    for (int p = 0; p < 3; p++){
      float o[4];
#pragma unroll
      for (int jj = 0; jj < 4; jj++){
        float s = 0.f;
#pragma unroll
        for (int k = 0; k < 9; k++) s = fmaf(ga[k], pr[p][jj+k], s);
        o[jj] = s;
      }
      *reinterpret_cast<float4*>(&hs[p][hr][oc]) = make_float4(o[0],o[1],o[2],o[3]);
    }
  }
  __syncthreads();

  // ---- vertical Gaussian + Harris R, 2 rows x 4 cols per thread ----
  const int c4o = tid & 15;
  const int r0o = (tid >> 4) * 2;
  float4 sA[3], sB[3];
#pragma unroll
  for (int p = 0; p < 3; p++){
    float4 a0 = make_float4(0,0,0,0), a1 = make_float4(0,0,0,0);
#pragma unroll
    for (int k = 0; k < 10; k++){
      float4 hv = *reinterpret_cast<const float4*>(&hs[p][r0o+k][c4o*4]);
      if (k < 9){
        a0.x = fmaf(ga[k], hv.x, a0.x); a0.y = fmaf(ga[k], hv.y, a0.y);
        a0.z = fmaf(ga[k], hv.z, a0.z); a0.w = fmaf(ga[k], hv.w, a0.w);
      }
      if (k >= 1){
        a1.x = fmaf(ga[k-1], hv.x, a1.x); a1.y = fmaf(ga[k-1], hv.y, a1.y);
        a1.z = fmaf(ga[k-1], hv.z, a1.z); a1.w = fmaf(ga[k-1], hv.w, a1.w);
      }
    }
    sA[p] = a0; sB[p] = a1;
  }

  float* Rb = R + (size_t)n * (size_t)(IMH*IMW);
  {
    float4 o0, o1;
    float s0, s1, s2, det, tr;
    s0=sA[0].x; s1=sA[1].x; s2=sA[2].x; det=s0*s1-s2*s2; tr=s0+s1; o0.x=det-ALPHA*tr*tr;
    s0=sA[0].y; s1=sA[1].y; s2=sA[2].y; det=s0*s1-s2*s2; tr=s0+s1; o0.y=det-ALPHA*tr*tr;
    s0=sA[0].z; s1=sA[1].z; s2=sA[2].z; det=s0*s1-s2*s2; tr=s0+s1; o0.z=det-ALPHA*tr*tr;
    s0=sA[0].w; s1=sA[1].w; s2=sA[2].w; det=s0*s1-s2*s2; tr=s0+s1; o0.w=det-ALPHA*tr*tr;
    s0=sB[0].x; s1=sB[1].x; s2=sB[2].x; det=s0*s1-s2*s2; tr=s0+s1; o1.x=det-ALPHA*tr*tr;
    s0=sB[0].y; s1=sB[1].y; s2=sB[2].y; det=s0*s1-s2*s2; tr=s0+s1; o1.y=det-ALPHA*tr*tr;
    s0=sB[0].z; s1=sB[1].z; s2=sB[2].z; det=s0*s1-s2*s2; tr=s0+s1; o1.z=det-ALPHA*tr*tr;
    s0=sB[0].w; s1=sB[1].w; s2=sB[2].w; det=s0*s1-s2*s2; tr=s0+s1; o1.w=det-ALPHA*tr*tr;

    int orow = R0 + r0o;
    int ocol = C0 + c4o*4;
    *reinterpret_cast<float4*>(&Rb[(size_t)orow*IMW + ocol])     = o0;
    *reinterpret_cast<float4*>(&Rb[(size_t)(orow+1)*IMW + ocol]) = o1;
  }
}

// ---------------------------------------------------------------------------
// Median: 3-pass radix select (8 / 12 / 12 bits) on monotonic key transform
// hist8 uses 32 histogram replicas: addr = bin*32 + (lane&31) -> bank ==
// lane&31 (never a cross-lane bank conflict); same-address collisions only
// between lane l and l+32 (2-way, free).
// ---------------------------------------------------------------------------
__global__ __launch_bounds__(256) void hist8_kernel(
    const float4* __restrict__ R4, uint32_t* __restrict__ h)
{
  __shared__ uint32_t lh[256*32];
  for (int i = threadIdx.x; i < 256*32; i += 256) lh[i] = 0;
  __syncthreads();
  const int copy = threadIdx.x & 31;
  const int stride = gridDim.x * 256;
  for (int i = blockIdx.x*256 + threadIdx.x; i < NPIX/4; i += stride){
    float4 v = R4[i];
    atomicAdd(&lh[(fkey(v.x) >> 24)*32 + copy], 1u);
    atomicAdd(&lh[(fkey(v.y) >> 24)*32 + copy], 1u);
    atomicAdd(&lh[(fkey(v.z) >> 24)*32 + copy], 1u);
    atomicAdd(&lh[(fkey(v.w) >> 24)*32 + copy], 1u);
  }
  __syncthreads();
  // reduce 32 copies of bin t (rotated start to spread banks)
  {
    const int t = threadIdx.x;
    uint32_t s = 0;
#pragma unroll
    for (int i = 0; i < 32; i++) s += lh[t*32 + ((t + i) & 31)];
    if (s) atomicAdd(&h[t], s);
  }
}

__global__ __launch_bounds__(256) void hist12_kernel(
    const float4* __restrict__ R4, uint32_t* __restrict__ h,
    const uint32_t* __restrict__ state, int phase)
{
  __shared__ uint32_t lh[4096];
  for (int i = threadIdx.x; i < 4096; i += 256) lh[i] = 0;
  __syncthreads();
  const uint32_t target = (phase == 0) ? state[0] : ((state[0] << 12) | state[2]);
  const int shift = (phase == 0) ? 24 : 12;
  const int stride = gridDim.x * 256;
  for (int i = blockIdx.x*256 + threadIdx.x; i < NPIX/4; i += stride){
    float4 v = R4[i];
    uint32_t k;
    k = fkey(v.x); if ((k >> shift) == target) atomicAdd(&lh[(k >> (shift-12)) & 0xfffu], 1u);
    k = fkey(v.y); if ((k >> shift) == target) atomicAdd(&lh[(k >> (shift-12)) & 0xfffu], 1u);
    k = fkey(v.z); if ((k >> shift) == target) atomicAdd(&lh[(k >> (shift-12)) & 0xfffu], 1u);
    k = fkey(v.w); if ((k >> shift) == target) atomicAdd(&lh[(k >> (shift-12)) & 0xfffu], 1u);
  }
  __syncthreads();
  for (int i = threadIdx.x; i < 4096; i += 256)
    if (lh[i]) atomicAdd(&h[i], lh[i]);
}

__global__ __launch_bounds__(256) void select_kernel(
    const uint32_t* __restrict__ h, uint32_t* __restrict__ state,
    int nbins, int phase)
{
  __shared__ uint32_t sc[256];
  const int t = threadIdx.x;
  const int chunk = nbins >> 8;   // 1 or 16
  uint32_t lsum = 0;
  for (int i = 0; i < chunk; i++) lsum += h[t*chunk + i];
  sc[t] = lsum;
  __syncthreads();
  for (int off = 1; off < 256; off <<= 1){
    uint32_t v = (t >= off) ? sc[t-off] : 0u;
    __syncthreads();
    sc[t] += v;
    __syncthreads();
  }
  const uint32_t excl = sc[t] - lsum;
  const uint32_t rank = (phase == 0) ? (uint32_t)MEDRANK : state[(phase == 1) ? 1 : 3];
  if (rank >= excl && rank < excl + lsum){
    uint32_t cum = excl;
    for (int i = 0; i < chunk; i++){
      uint32_t c = h[t*chunk + i];
      if (rank < cum + c){
        uint32_t bin = (uint32_t)(t*chunk + i);
        if (phase == 0){ state[0] = bin; state[1] = rank - cum; }
        else if (phase == 1){ state[2] = bin; state[3] = rank - cum; }
        else {
          uint32_t key = (state[0] << 24) | (state[2] << 12) | bin;
          uint32_t u = (key & 0x80000000u) ? (key & 0x7fffffffu) : ~key;
          state[4] = u;
        }
        break;
      }
      cum += c;
    }
  }
}

// ---------------------------------------------------------------------------
// Threshold + 7x7 maxpool NMS. Tile 64x64, halo 3. Padded strides.
// ---------------------------------------------------------------------------
#define PT 64
__global__ __launch_bounds__(256) void nms_kernel(
    const float* __restrict__ R, const uint32_t* __restrict__ state,
    float* __restrict__ out)
{
  __shared__ float xt[PT+6][76];   // 70 rows, cols C0-4..C0+67
  __shared__ float hm[PT+6][68];   // 70 rows, cols C0..C0+63

  const int tid = threadIdx.x;
  const int C0 = blockIdx.x * PT;
  const int R0 = blockIdx.y * PT;
  const int n  = blockIdx.z;
  const float med = __uint_as_float(state[4]);
  const float* Rb = R + (size_t)n * (size_t)(IMH*IMW);

  for (int u = tid; u < 70*18; u += 256){
    int r  = u / 18, c4 = u % 18;
    int gr = R0 - 3 + r;
    int gc = C0 - 4 + c4*4;
    float4 v;
    if (gr >= 0 && gr < IMH && gc >= 0 && gc + 3 < IMW){
      v = *reinterpret_cast<const float4*>(&Rb[(size_t)gr*IMW + gc]);
      v.x = v.x > med ? v.x : 0.f;
      v.y = v.y > med ? v.y : 0.f;
      v.z = v.z > med ? v.z : 0.f;
      v.w = v.w > med ? v.w : 0.f;
    } else {
      float t0, t1, t2, t3;
      t0 = (gr>=0&&gr<IMH&&gc+0>=0&&gc+0<IMW) ? Rb[(size_t)gr*IMW+gc+0] : -INFINITY;
      t1 = (gr>=0&&gr<IMH&&gc+1>=0&&gc+1<IMW) ? Rb[(size_t)gr*IMW+gc+1] : -INFINITY;
      t2 = (gr>=0&&gr<IMH&&gc+2>=0&&gc+2<IMW) ? Rb[(size_t)gr*IMW+gc+2] : -INFINITY;
      t3 = (gr>=0&&gr<IMH&&gc+3>=0&&gc+3<IMW) ? Rb[(size_t)gr*IMW+gc+3] : -INFINITY;
      v.x = (t0 == -INFINITY) ? t0 : (t0 > med ? t0 : 0.f);
      v.y = (t1 == -INFINITY) ? t1 : (t1 > med ? t1 : 0.f);
      v.z = (t2 == -INFINITY) ? t2 : (t2 > med ? t2 : 0.f);
      v.w = (t3 == -INFINITY) ? t3 : (t3 > med ? t3 : 0.f);
    }
    *reinterpret_cast<float4*>(&xt[r][c4*4]) = v;
  }
  __syncthreads();

  for (int u = tid; u < 70*16; u += 256){
    int r = u / 16, c4 = u % 16;
    float4 t0 = *reinterpret_cast<const float4*>(&xt[r][c4*4]);
    float4 t1 = *reinterpret_cast<const float4*>(&xt[r][c4*4+4]);
    float4 t2 = *reinterpret_cast<const float4*>(&xt[r][c4*4+8]);
    float w[12];
    w[0]=t0.x; w[1]=t0.y; w[2]=t0.z; w[3]=t0.w;
    w[4]=t1.x; w[5]=t1.y; w[6]=t1.z; w[7]=t1.w;
    w[8]=t2.x; w[9]=t2.y; w[10]=t2.z; w[11]=t2.w;
    float o[4];
#pragma unroll
    for (int j = 0; j < 4; j++){
      float m = w[j+1];
#pragma unroll
      for (int k = 2; k <= 7; k++) m = fmaxf(m, w[j+k]);
      o[j] = m;
    }
    *reinterpret_cast<float4*>(&hm[r][c4*4]) = make_float4(o[0],o[1],o[2],o[3]);
  }
  __syncthreads();

  const int c4o = tid & 15;
  const int r0o = (tid >> 4) * 4;
  float4 hv[10];
#pragma unroll
  for (int k = 0; k < 10; k++)
    hv[k] = *reinterpret_cast<const float4*>(&hm[r0o+k][c4o*4]);

  float* ob = out + (size_t)n * (size_t)(IMH*IMW);
#pragma unroll
  for (int i = 0; i < 4; i++){
    float4 y = hv[i];
#pragma unroll
    for (int k = 1; k < 7; k++){
      float4 t = hv[i+k];
      y.x = fmaxf(y.x, t.x); y.y = fmaxf(y.y, t.y);
      y.z = fmaxf(y.z, t.z); y.w = fmaxf(y.w, t.w);
    }
    float4 c = *reinterpret_cast<const float4*>(&xt[r0o+i+3][c4o*4+4]);
    float4 o;
    o.x = (c.x == y.x) ? c.x : 0.f;
    o.y = (c.y == y.y) ? c.y : 0.f;
    o.z = (c.z == y.z) ? c.z : 0.f;
    o.w = (c.w == y.w) ? c.w : 0.f;
    *reinterpret_cast<float4*>(&ob[(size_t)(R0+r0o+i)*IMW + C0 + c4o*4]) = o;
  }
}

// ---------------------------------------------------------------------------
extern "C" void kernel_launch(void* const* d_in, const int* in_sizes, int n_in,
                              void* d_out, int out_size, void* d_ws, size_t ws_size,
                              hipStream_t stream)
{
  (void)in_sizes; (void)n_in; (void)out_size; (void)ws_size;
  const float* x  = (const float*)d_in[0];
  const float* sw = (const float*)d_in[1];
  const float* gw = (const float*)d_in[2];
  float* out = (float*)d_out;

  float* R = (float*)d_ws;
  uint32_t* hist = (uint32_t*)((char*)d_ws + (size_t)NPIX * sizeof(float));
  uint32_t* h8    = hist;
  uint32_t* h12a  = hist + 256;
  uint32_t* h12b  = hist + 256 + 4096;
  uint32_t* state = hist + 256 + 4096 + 4096;

  hipMemsetAsync(hist, 0, (256 + 4096 + 4096) * sizeof(uint32_t), stream);

  front_kernel<<<dim3(IMW/TW, IMH/TH, NB), 256, 0, stream>>>(x, sw, gw, R);

  hist8_kernel <<<1024, 256, 0, stream>>>((const float4*)R, h8);
  select_kernel<<<1,    256, 0, stream>>>(h8, state, 256, 0);
  hist12_kernel<<<1024, 256, 0, stream>>>((const float4*)R, h12a, state, 0);
  select_kernel<<<1,    256, 0, stream>>>(h12a, state, 4096, 1);
  hist12_kernel<<<1024, 256, 0, stream>>>((const float4*)R, h12b, state, 1);
  select_kernel<<<1,    256, 0, stream>>>(h12b, state, 4096, 2);

  nms_kernel<<<dim3(IMW/PT, IMH/PT, NB), 256, 0, stream>>>(R, state, out);
}